// Round 7
// baseline (433.292 us; speedup 1.0000x reference)
//
#include <hip/hip_runtime.h>

typedef __bf16 bf16x8 __attribute__((ext_vector_type(8)));
typedef float  f32x4  __attribute__((ext_vector_type(4)));
typedef unsigned short u16;

#define N_EMBD 768
#define T_LEN 1024
#define S_LEN 257
#define S_PAD 320
#define BATCH 8
#define NH 12
#define BH (BATCH*NH)
#define HD 64

// native f32->bf16 (RNE, 1 instr on gfx950)
__device__ __forceinline__ u16 f2b(float f){
  union{ __bf16 h; u16 u; } v; v.h=(__bf16)f; return v.u;
}
__device__ __forceinline__ float b2f(u16 h){
  union{unsigned u; float f;} v; v.u=((unsigned)h)<<16;
  return v.f;
}
__device__ __forceinline__ void gl_lds16(const void* g, void* l){
  __builtin_amdgcn_global_load_lds((const __attribute__((address_space(1))) void*)g,
                                   (__attribute__((address_space(3))) void*)l, 16, 0, 0);
}

// DPP 16-lane reductions — pure VALU
template<int C> __device__ __forceinline__ float dpp_mov_f(float x){
  union{float f;int i;} u; u.f=x;
  u.i = __builtin_amdgcn_mov_dpp(u.i, C, 0xf, 0xf, true);
  return u.f;
}
__device__ __forceinline__ float red16_add(float x){
  x = x + dpp_mov_f<0xB1>(x);
  x = x + dpp_mov_f<0x4E>(x);
  x = x + dpp_mov_f<0x141>(x);
  x = x + dpp_mov_f<0x140>(x);
  return x;
}

// ------------- merged prep: weight transpose+cvt(+q-scale), enc cvt, ln1,
//               scaled-bias copies --------------------------------------
__global__ void prep_all(const float* __restrict__ s0,const float* __restrict__ s1,
                         const float* __restrict__ s2,const float* __restrict__ s3,
                         const float* __restrict__ s4,const float* __restrict__ s5,
                         u16* __restrict__ d0,u16* __restrict__ d1,
                         u16* __restrict__ d2,u16* __restrict__ d3,
                         u16* __restrict__ d4,u16* __restrict__ d5,
                         const float* __restrict__ enc, u16* __restrict__ enc_bf,
                         const float* __restrict__ xin, const float* __restrict__ g1,
                         const float* __restrict__ b1, u16* __restrict__ hbuf,
                         const float* __restrict__ attn_b, const float* __restrict__ cross_b,
                         float* __restrict__ sb_attn, float* __restrict__ sb_cross){
  __shared__ u16 tile[64][68];
  int id=blockIdx.x;
  if(id>=5894){
    int i=(id-5894)*256+threadIdx.x;
    if(i<2304)      sb_attn[i]       = attn_b[i]       *((i     <768)?0.125f:1.f);
    else if(i<4608) sb_cross[i-2304] = cross_b[i-2304] *((i-2304<768)?0.125f:1.f);
    return;
  }
  if(id>=3846){
    // ---- ln1 ----
    int row  = (id-3846)*4 + (threadIdx.x>>6);
    int lane = threadIdx.x&63;
    size_t base = (size_t)row*N_EMBD;
    float v[12];
#pragma unroll
    for(int p=0;p<3;p++){
      int col = p*256 + lane*4;
      float4 f = *(const float4*)&xin[base+col];
      v[p*4]=f.x; v[p*4+1]=f.y; v[p*4+2]=f.z; v[p*4+3]=f.w;
    }
    float s=0.f, s2=0.f;
#pragma unroll
    for(int i=0;i<12;i++){ s+=v[i]; s2+=v[i]*v[i]; }
#pragma unroll
    for(int off=1; off<64; off<<=1){ s += __shfl_xor(s,off); s2 += __shfl_xor(s2,off); }
    float mean = s*(1.f/N_EMBD);
    float var  = s2*(1.f/N_EMBD) - mean*mean;
    float rstd = rsqrtf(var + 1e-5f);
#pragma unroll
    for(int p=0;p<3;p++){
      int col = p*256 + lane*4;
#pragma unroll
      for(int j=0;j<4;j++){
        hbuf[base+col+j] = f2b((v[p*4+j]-mean)*rstd*g1[col+j] + b1[col+j]);
      }
    }
    return;
  }
  if(id>=2304){
    // ---- enc convert ----
    int i = (id-2304)*256 + threadIdx.x;
    float4 f = *(const float4*)&enc[i*4];
    ushort4 u; u.x=f2b(f.x); u.y=f2b(f.y); u.z=f2b(f.z); u.w=f2b(f.w);
    *(ushort4*)&enc_bf[i*4] = u;
    return;
  }
  // ---- weight transpose (+ 0.125 fold on q-columns of attn_w/cross_w) ----
  const float* in; u16* out; int K,N,t;
  if(id<432)      {in=s0;out=d0;K=768;N=2304;t=id;}
  else if(id<864) {in=s1;out=d1;K=768;N=2304;t=id-432;}
  else if(id<1008){in=s2;out=d2;K=768;N=768;t=id-864;}
  else if(id<1152){in=s3;out=d3;K=768;N=768;t=id-1008;}
  else if(id<1728){in=s4;out=d4;K=768;N=3072;t=id-1152;}
  else            {in=s5;out=d5;K=3072;N=768;t=id-1728;}
  int tiles_n=N>>6;
  int k0=(t/tiles_n)<<6, n0=(t%tiles_n)<<6;
  float qs = (id<864 && n0<768) ? 0.125f : 1.f;   // whole 64-tile inside q-part
  int tr = threadIdx.x>>4;
  int tc = (threadIdx.x&15)*4;
#pragma unroll
  for(int i=0;i<4;i++){
    float4 f = *(const float4*)&in[(size_t)(k0+tr+i*16)*N + n0 + tc];
    tile[tr+i*16][tc+0]=f2b(f.x*qs); tile[tr+i*16][tc+1]=f2b(f.y*qs);
    tile[tr+i*16][tc+2]=f2b(f.z*qs); tile[tr+i*16][tc+3]=f2b(f.w*qs);
  }
  __syncthreads();
#pragma unroll
  for(int i=0;i<4;i++){
    int n = n0+tr+i*16;
    ushort4 u;
    u.x=tile[tc+0][tr+i*16]; u.y=tile[tc+1][tr+i*16];
    u.z=tile[tc+2][tr+i*16]; u.w=tile[tc+3][tr+i*16];
    *(ushort4*)&out[(size_t)n*K + k0 + tc] = u;
  }
}

// ------------- layernorm: one wave per row of 768, f32 in -> bf16 out -----
__global__ void ln_kernel(const float* __restrict__ x, const float* __restrict__ g,
                          const float* __restrict__ bta, u16* __restrict__ out){
  int row  = blockIdx.x*4 + (threadIdx.x>>6);
  int lane = threadIdx.x&63;
  size_t base = (size_t)row*N_EMBD;
  float v[12];
#pragma unroll
  for(int p=0;p<3;p++){
    int col = p*256 + lane*4;
    float4 f = *(const float4*)&x[base+col];
    v[p*4]=f.x; v[p*4+1]=f.y; v[p*4+2]=f.z; v[p*4+3]=f.w;
  }
  float s=0.f, s2=0.f;
#pragma unroll
  for(int i=0;i<12;i++){ s+=v[i]; s2+=v[i]*v[i]; }
#pragma unroll
  for(int off=1; off<64; off<<=1){ s += __shfl_xor(s,off); s2 += __shfl_xor(s2,off); }
  float mean = s*(1.f/N_EMBD);
  float var  = s2*(1.f/N_EMBD) - mean*mean;
  float rstd = rsqrtf(var + 1e-5f);
#pragma unroll
  for(int p=0;p<3;p++){
    int col = p*256 + lane*4;
#pragma unroll
    for(int j=0;j<4;j++){
      out[base+col+j] = f2b((v[p*4+j]-mean)*rstd*g[col+j] + bta[col+j]);
    }
  }
}

// ---------------- GEMM: C = A(M,K) @ Wt(N,K)^T + bias, fused epilogues ----
// BM=128, BK=64 (or 128 via BK2 double-stage), BN in {64,128}. XOR-swizzled
// LDS. Round-0 proven sync structure. BK2=1: issue BOTH 64-wide sub-stages
// before ONE barrier, compute both after -> halves the number of vmcnt(0)
// barrier-drain events at unchanged occupancy (only used where the grid caps
// blocks/CU at 3 anyway, so the 48KB LDS costs nothing). Accumulation order
// per output element is the identical k0, k0+64 sequence -> bit-identical.
enum { M_QKV_SELF=0, M_Q_CROSS=1, M_KV_CROSS=2, M_RESID_F32=3,
       M_RESID_INPLACE=4, M_GELU=5, M_RESID_OUT=6 };

template<int MI, int BN>
__device__ __forceinline__ void gemm_compute(const u16* __restrict__ As,
                                             const u16* __restrict__ Bs,
                                             f32x4 (&acc)[MI][4],
                                             int wm,int wn,int lrow,int pa){
  bf16x8 af[MI][2], bfr[4][2];
#pragma unroll
  for(int i=0;i<MI;i++){
    const u16* ab=&As[(wm+i*16+lrow)*64];
    af[i][0]=*(const bf16x8*)(ab+pa*8);
    af[i][1]=*(const bf16x8*)(ab+(pa^4)*8);
  }
#pragma unroll
  for(int i=0;i<4;i++){
    const u16* bb=&Bs[(wn+i*16+lrow)*64];
    bfr[i][0]=*(const bf16x8*)(bb+pa*8);
    bfr[i][1]=*(const bf16x8*)(bb+(pa^4)*8);
  }
#pragma unroll
  for(int h=0;h<2;h++)
#pragma unroll
    for(int mi=0;mi<MI;mi++)
#pragma unroll
      for(int ni=0;ni<4;ni++)
        acc[mi][ni] = __builtin_amdgcn_mfma_f32_16x16x32_bf16(af[mi][h], bfr[ni][h], acc[mi][ni], 0,0,0);
}

template<int MODE, int BN, int BK2>
__device__ __forceinline__ void gemm_body(u16* __restrict__ As, u16* __restrict__ Bs,
                        const u16* __restrict__ A, const u16* __restrict__ Wt,
                        const float* __restrict__ bias,
                        void* out0, void* out1, void* out2, const void* resid,
                        int M, int K, int Ntiles, int Mtl, int bid){
  constexpr int MI = (BN==128)?4:2;
  int tid=threadIdx.x, wave=tid>>6, lane=tid&63;

  int mt, nt;
  if((Mtl&7)==0){
    int xcd=bid&7, j=bid>>3, bpx=Mtl>>3;
    int band=j/Ntiles; nt=j-band*Ntiles; mt=xcd*bpx+band;
  } else { mt=bid/Ntiles; nt=bid-mt*Ntiles; }
  int m0=mt*128, n0=nt*BN;

  int wm = (BN==128)? (wave>>1)*64 : wave*32;
  int wn = (BN==128)? (wave&1)*64  : 0;
  int lrow=lane&15, quad=lane>>4;
  f32x4 acc[MI][4];
  f32x4 z = {0.f,0.f,0.f,0.f};
#pragma unroll
  for(int i=0;i<MI;i++)
#pragma unroll
    for(int j=0;j<4;j++) acc[i][j]=z;

  int srow  = wave*8 + (lane>>3);
  int c_src = (lane&7) ^ ((lane>>3)&7);
  int pa = quad ^ (lrow&7);

  // hoisted K-invariant stage base pointers (clamp + row*K done once)
  const u16* ap[4];
#pragma unroll
  for(int i=0;i<4;i++){
    int ga = min(m0 + i*32 + srow, M-1);
    ap[i] = A + (size_t)ga*K + c_src*8;
  }
  const u16* bp[BN/32];
#pragma unroll
  for(int i=0;i<BN/32;i++)
    bp[i] = Wt + (size_t)(n0 + i*32 + srow)*K + c_src*8;

  for(int k0=0;k0<K;k0+=(BK2?128:64)){
#pragma unroll
    for(int i=0;i<4;i++)
      gl_lds16(ap[i] + k0, &As[(i*32+wave*8)*64]);
#pragma unroll
    for(int i=0;i<BN/32;i++)
      gl_lds16(bp[i] + k0, &Bs[(i*32+wave*8)*64]);
    if(BK2){
#pragma unroll
      for(int i=0;i<4;i++)
        gl_lds16(ap[i] + k0+64, &As[128*64 + (i*32+wave*8)*64]);
#pragma unroll
      for(int i=0;i<BN/32;i++)
        gl_lds16(bp[i] + k0+64, &Bs[BN*64 + (i*32+wave*8)*64]);
    }
    __syncthreads();
    gemm_compute<MI,BN>(As,Bs,acc,wm,wn,lrow,pa);
    if(BK2) gemm_compute<MI,BN>(As+128*64, Bs+BN*64, acc, wm,wn,lrow,pa);
    __syncthreads();
  }

#pragma unroll
  for(int ni=0;ni<4;ni++){
    int n = n0 + wn + ni*16 + lrow;
    float bv = bias[n];
#pragma unroll
    for(int mi=0;mi<MI;mi++){
      int mbase = m0 + wm + mi*16 + quad*4;
      float cr[4];
#pragma unroll
      for(int r=0;r<4;r++) cr[r]=acc[mi][ni][r]+bv;

      if constexpr (MODE==M_QKV_SELF){
        int part=n/768, nn=n-part*768;
        int hh=nn>>6, dd=nn&63;
        int b=mbase>>10, t0=mbase&1023;
        size_t bh=(size_t)(b*NH+hh);
        if(part==0){   // q pre-scaled by 0.125 via weight/bias fold
#pragma unroll
          for(int r=0;r<4;r++) ((u16*)out0)[(bh*T_LEN+t0+r)*HD+dd]=f2b(cr[r]);
        } else if(part==1){
#pragma unroll
          for(int r=0;r<4;r++) ((u16*)out1)[(bh*T_LEN+t0+r)*HD+dd]=f2b(cr[r]);
        } else {
          ushort4 pk; pk.x=f2b(cr[0]); pk.y=f2b(cr[1]); pk.z=f2b(cr[2]); pk.w=f2b(cr[3]);
          *(ushort4*)&((u16*)out2)[(bh*HD+dd)*T_LEN+t0]=pk;
        }
      } else if constexpr (MODE==M_Q_CROSS){
        int b=mbase>>10, t0=mbase&1023;
        int hh=n>>6, dd=n&63;
        size_t bh=(size_t)(b*NH+hh);
#pragma unroll
        for(int r=0;r<4;r++) ((u16*)out0)[(bh*T_LEN+t0+r)*HD+dd]=f2b(cr[r]);
      } else if constexpr (MODE==M_KV_CROSS){
        int part=n/768, nn=n-part*768;
        int hh=nn>>6, dd=nn&63;
#pragma unroll
        for(int r=0;r<4;r++){
          int m=mbase+r;
          if(m<M){
            int b=m/S_LEN, s=m-b*S_LEN;
            size_t bh=(size_t)(b*NH+hh);
            if(part==0) ((u16*)out0)[(bh*S_PAD+s)*HD+dd]=f2b(cr[r]);
            else        ((u16*)out1)[(bh*HD+dd)*S_PAD+s]=f2b(cr[r]);
          }
        }
      } else if constexpr (MODE==M_RESID_F32){
        const float* x=(const float*)resid;
#pragma unroll
        for(int r=0;r<4;r++){ int m=mbase+r;
          ((float*)out0)[(size_t)m*768+n]=x[(size_t)m*768+n]+cr[r]; }
      } else if constexpr (MODE==M_RESID_INPLACE){
#pragma unroll
        for(int r=0;r<4;r++){ int m=mbase+r;
          ((float*)out0)[(size_t)m*768+n]+=cr[r]; }
      } else if constexpr (MODE==M_GELU){
#pragma unroll
        for(int r=0;r<4;r++){
          int m=mbase+r;
          float uu=cr[r];
          float zz=0.7978845608028654f*(uu+0.044715f*uu*uu*uu);
          float e=__expf(fminf(2.f*zz, 80.f));
          ((u16*)out0)[(size_t)m*3072+n]=f2b(uu*e*__builtin_amdgcn_rcpf(e+1.f));
        }
      } else { // M_RESID_OUT -> float32 output
        const float* x=(const float*)resid;
#pragma unroll
        for(int r=0;r<4;r++){ int m=mbase+r;
          ((float*)out0)[(size_t)m*768+n]=x[(size_t)m*768+n]+cr[r]; }
      }
    }
  }
}

template<int MODE, int BN, int BK2>
__global__ __launch_bounds__(256,3)
void gemm_bt(const u16* __restrict__ A, const u16* __restrict__ Wt,
             const float* __restrict__ bias,
             void* out0, void* out1, void* out2, const void* resid,
             int M, int K, int Ntiles){
  __shared__ u16 As[(1+BK2)*128*64];
  __shared__ u16 Bs[(1+BK2)*BN*64];
  gemm_body<MODE,BN,BK2>(As,Bs,A,Wt,bias,out0,out1,out2,resid,M,K,Ntiles,
                         gridDim.x/Ntiles, blockIdx.x);
}

// Q_cross (768 blocks) + KV_cross (408 blocks) fused into one launch.
__global__ __launch_bounds__(256,3)
void gemm_cross(const u16* __restrict__ hbuf, const u16* __restrict__ cwT,
                const float* __restrict__ sbc, const u16* __restrict__ encbf,
                void* Qc, void* Kc, void* Vct){
  __shared__ u16 As[128*64];
  __shared__ u16 Bs[64*64];
  if(blockIdx.x<768)
    gemm_body<M_Q_CROSS,64,0>(As,Bs,hbuf,cwT,sbc,Qc,nullptr,nullptr,nullptr,
                              8192,768,12, 64, blockIdx.x);
  else
    gemm_body<M_KV_CROSS,64,0>(As,Bs,encbf,cwT+768*768,sbc+768,Kc,Vct,nullptr,nullptr,
                               2056,768,24, 17, blockIdx.x-768);
}

// ---------------- flash attention v4 (round-4 proven): LDS-staged K/V,
// double-buffered, fixed-max softmax, XCD-local blocks ----------------------
template<bool CAUSAL>
__global__ __launch_bounds__(256,2)
void flash_attn(const u16* __restrict__ Q, const u16* __restrict__ Kk,
                const u16* __restrict__ V, u16* __restrict__ O,
                int Skey, int Spad){
  __shared__ u16 KT[2][64*64];
  __shared__ u16 VT[2][64*64];
  __shared__ u16 Plds[4][16][72];
  int bh = blockIdx.x % BH;
  int qbi= blockIdx.x / BH;
  int qb = CAUSAL ? (15-qbi) : qbi;          // heavy blocks dispatched first
  int b=bh/NH, hh=bh-b*NH;
  int wave=threadIdx.x>>6, lane=threadIdx.x&63;
  int lrow=lane&15, quad=lane>>4;
  const u16* Qp=Q+(size_t)bh*T_LEN*HD;
  const u16* Kp=Kk+(size_t)bh*Spad*HD;
  const u16* Vp=V+(size_t)bh*HD*Spad;
  u16* Op=O+(size_t)b*T_LEN*N_EMBD+hh*HD;
  int q0 = qb*64 + wave*16;

  int r0    = wave*8 + (lane>>3);
  int c_src = (lane&7) ^ ((lane>>3)&7);

  bf16x8 aq0=*(const bf16x8*)&Qp[(size_t)(q0+lrow)*HD + quad*8];
  bf16x8 aq1=*(const bf16x8*)&Qp[(size_t)(q0+lrow)*HD + 32 + quad*8];

  f32x4 oacc[4];
  f32x4 z={0.f,0.f,0.f,0.f};
#pragma unroll
  for(int i=0;i<4;i++) oacc[i]=z;
  float lsum[4]={0.f,0.f,0.f,0.f};

  int nt = CAUSAL ? (qb+1) : ((Skey+63)>>6);

  {
    gl_lds16(Kp + (size_t)r0*HD        + c_src*8, &KT[0][(wave*8)*64]);
    gl_lds16(Kp + (size_t)(r0+32)*HD   + c_src*8, &KT[0][(32+wave*8)*64]);
    gl_lds16(Vp + (size_t)r0*Spad      + c_src*8, &VT[0][(wave*8)*64]);
    gl_lds16(Vp + (size_t)(r0+32)*Spad + c_src*8, &VT[0][(32+wave*8)*64]);
  }
  __syncthreads();

  int p0 = quad ^ (lrow&7);

  for(int it=0; it<nt; it++){
    int bb = it&1;
    int kt = it*64;
    if(it+1<nt){
      int ktn=(it+1)*64;
      gl_lds16(Kp + (size_t)(ktn+r0)*HD      + c_src*8, &KT[bb^1][(wave*8)*64]);
      gl_lds16(Kp + (size_t)(ktn+r0+32)*HD   + c_src*8, &KT[bb^1][(32+wave*8)*64]);
      gl_lds16(Vp + (size_t)r0*Spad      + ktn + c_src*8, &VT[bb^1][(wave*8)*64]);
      gl_lds16(Vp + (size_t)(r0+32)*Spad + ktn + c_src*8, &VT[bb^1][(32+wave*8)*64]);
    }
    f32x4 s[4];
#pragma unroll
    for(int g=0;g<4;g++){
      const u16* kb=&KT[bb][(g*16+lrow)*64];
      bf16x8 bk0=*(const bf16x8*)(kb+p0*8);
      bf16x8 bk1=*(const bf16x8*)(kb+(p0^4)*8);
      s[g]=z;
      s[g]=__builtin_amdgcn_mfma_f32_16x16x32_bf16(aq0,bk0,s[g],0,0,0);
      s[g]=__builtin_amdgcn_mfma_f32_16x16x32_bf16(aq1,bk1,s[g],0,0,0);
    }
    bool domask = (it==nt-1);
#pragma unroll
    for(int r=0;r<4;r++){
      float sv0=s[0][r], sv1=s[1][r], sv2=s[2][r], sv3=s[3][r];
      if(domask){
        if(CAUSAL){
          int q=q0+quad*4+r;
          if(kt+lrow    >q) sv0=-3.0e38f;
          if(kt+16+lrow >q) sv1=-3.0e38f;
          if(kt+32+lrow >q) sv2=-3.0e38f;
          if(kt+48+lrow >q) sv3=-3.0e38f;
        } else {
          if(kt+lrow    >=Skey) sv0=-3.0e38f;
          if(kt+16+lrow >=Skey) sv1=-3.0e38f;
          if(kt+32+lrow >=Skey) sv2=-3.0e38f;
          if(kt+48+lrow >=Skey) sv3=-3.0e38f;
        }
      }
      float p0e=__expf(sv0), p1e=__expf(sv1);
      float p2e=__expf(sv2), p3e=__expf(sv3);
      lsum[r] += (p0e+p1e)+(p2e+p3e);
      Plds[wave][quad*4+r][lrow]    = f2b(p0e);
      Plds[wave][quad*4+r][16+lrow] = f2b(p1e);
      Plds[wave][quad*4+r][32+lrow] = f2b(p2e);
      Plds[wave][quad*4+r][48+lrow] = f2b(p3e);
    }
    bf16x8 ap0=*(const bf16x8*)&Plds[wave][lrow][quad*8];
    bf16x8 ap1=*(const bf16x8*)&Plds[wave][lrow][32+quad*8];
#pragma unroll
    for(int dt=0;dt<4;dt++){
      const u16* vb=&VT[bb][(dt*16+lrow)*64];
      bf16x8 bv0=*(const bf16x8*)(vb+p0*8);
      bf16x8 bv1=*(const bf16x8*)(vb+(p0^4)*8);
      oacc[dt]=__builtin_amdgcn_mfma_f32_16x16x32_bf16(ap0,bv0,oacc[dt],0,0,0);
      oacc[dt]=__builtin_amdgcn_mfma_f32_16x16x32_bf16(ap1,bv1,oacc[dt],0,0,0);
    }
    __syncthreads();
  }
  float linv[4];
#pragma unroll
  for(int r=0;r<4;r++) linv[r]=1.f/red16_add(lsum[r]);
#pragma unroll
  for(int dt=0;dt<4;dt++){
#pragma unroll
    for(int r=0;r<4;r++){
      int q=q0+quad*4+r;
      Op[(size_t)q*N_EMBD + dt*16 + lrow]=f2b(oacc[dt][r]*linv[r]);
    }
  }
}

// ---------------------------------------------------------------------------
extern "C" void kernel_launch(void* const* d_in, const int* in_sizes, int n_in,
                              void* d_out, int out_size, void* d_ws, size_t ws_size,
                              hipStream_t stream){
  const float* x_in   =(const float*)d_in[0];
  const float* enc    =(const float*)d_in[1];
  const float* ln1_g  =(const float*)d_in[2];
  const float* ln1_b  =(const float*)d_in[3];
  const float* ln2_g  =(const float*)d_in[4];
  const float* ln2_b  =(const float*)d_in[5];
  const float* ln3_g  =(const float*)d_in[6];
  const float* ln3_b  =(const float*)d_in[7];
  const float* attn_w =(const float*)d_in[8];
  const float* attn_b =(const float*)d_in[9];
  const float* attn_pw=(const float*)d_in[10];
  const float* attn_pb=(const float*)d_in[11];
  const float* cross_w=(const float*)d_in[12];
  const float* cross_b=(const float*)d_in[13];
  const float* cross_pw=(const float*)d_in[14];
  const float* cross_pb=(const float*)d_in[15];
  const float* fc_w   =(const float*)d_in[16];
  const float* fc_b   =(const float*)d_in[17];
  const float* proj_w =(const float*)d_in[18];
  const float* proj_b =(const float*)d_in[19];

  char* ws=(char*)d_ws;
  u16*  attn_wT  =(u16*)(ws + 0);           // 2304x768 bf16 (q-part pre-scaled)
  u16*  cross_wT =(u16*)(ws + 3538944);     // 2304x768    (q-part pre-scaled)
  u16*  attn_pwT =(u16*)(ws + 7077888);     // 768x768
  u16*  cross_pwT=(u16*)(ws + 8257536);     // 768x768
  u16*  fc_wT    =(u16*)(ws + 9437184);     // 3072x768
  u16*  proj_wT  =(u16*)(ws + 14155776);    // 768x3072
  float* xcur    =(float*)(ws + 18874368);  // 8192x768 f32
  u16*  hbuf     =(u16*)(ws + 44040192);    // 8192x768 bf16 (LN out / attn out)
  u16*  Qs       =(u16*)(ws + 56623104);    // 96x1024x64
  u16*  Ks       =(u16*)(ws + 69206016);
  u16*  Vst      =(u16*)(ws + 81788928);
  u16*  Qc       =(u16*)(ws + 94371840);
  u16*  hf       =(u16*)(ws + 56623104);    // 8192x3072, reuses Qs..Qc (MLP phase)
  u16*  Kc       =(u16*)(ws + 106954752);   // 96x320x64
  u16*  Vct      =(u16*)(ws + 110886912);   // 96x64x320
  u16*  enc_bf   =(u16*)(ws + 114819072);   // 2056x768 bf16
  float* sb_attn =(float*)(ws + 117977088); // 2304 f32 (q-part x0.125)
  float* sb_cross=(float*)(ws + 117986304); // 2304 f32 (q-part x0.125)

  dim3 blk(256);
  // merged: weight transpose (2304) + enc cvt (1542) + ln1 (2048) + bias (18)
  prep_all<<<5912,blk,0,stream>>>(attn_w, cross_w, attn_pw, cross_pw, fc_w, proj_w,
                                  attn_wT, cross_wT, attn_pwT, cross_pwT, fc_wT, proj_wT,
                                  enc, enc_bf, x_in, ln1_g, ln1_b, hbuf,
                                  attn_b, cross_b, sb_attn, sb_cross);

  // self-attention
  gemm_bt<M_QKV_SELF,128,0><<<1152,blk,0,stream>>>(hbuf, attn_wT, sb_attn,
      Qs, Ks, Vst, nullptr, 8192, 768, 18);
  flash_attn<true><<<1536,blk,0,stream>>>(Qs, Ks, Vst, hbuf, 1024, 1024);
  gemm_bt<M_RESID_F32,64,1><<<768,blk,0,stream>>>(hbuf, attn_pwT, attn_pb,
      xcur, nullptr, nullptr, x_in, 8192, 768, 12);

  // cross-attention
  ln_kernel<<<2048,blk,0,stream>>>(xcur, ln2_g, ln2_b, hbuf);
  gemm_cross<<<1176,blk,0,stream>>>(hbuf, cross_wT, sb_cross, enc_bf, Qc, Kc, Vct);
  flash_attn<false><<<1536,blk,0,stream>>>(Qc, Kc, Vct, hbuf, S_LEN, S_PAD);
  gemm_bt<M_RESID_INPLACE,64,1><<<768,blk,0,stream>>>(hbuf, cross_pwT, cross_pb,
      xcur, nullptr, nullptr, nullptr, 8192, 768, 12);

  // MLP
  ln_kernel<<<2048,blk,0,stream>>>(xcur, ln3_g, ln3_b, hbuf);
  gemm_bt<M_GELU,128,0><<<1536,blk,0,stream>>>(hbuf, fc_wT, fc_b,
      hf, nullptr, nullptr, nullptr, 8192, 768, 24);
  gemm_bt<M_RESID_OUT,64,1><<<768,blk,0,stream>>>(hf, proj_wT, proj_b,
      d_out, nullptr, nullptr, xcur, 8192, 3072, 12);
}

// Round 8
// 409.563 us; speedup vs baseline: 1.0579x; 1.0579x over previous
//
#include <hip/hip_runtime.h>

typedef __bf16 bf16x8 __attribute__((ext_vector_type(8)));
typedef float  f32x4  __attribute__((ext_vector_type(4)));
typedef unsigned short u16;

#define N_EMBD 768
#define T_LEN 1024
#define S_LEN 257
#define S_PAD 320
#define BATCH 8
#define NH 12
#define BH (BATCH*NH)
#define HD 64

// native f32->bf16 (RNE, 1 instr on gfx950)
__device__ __forceinline__ u16 f2b(float f){
  union{ __bf16 h; u16 u; } v; v.h=(__bf16)f; return v.u;
}
__device__ __forceinline__ float b2f(u16 h){
  union{unsigned u; float f;} v; v.u=((unsigned)h)<<16;
  return v.f;
}
__device__ __forceinline__ void gl_lds16(const void* g, void* l){
  __builtin_amdgcn_global_load_lds((const __attribute__((address_space(1))) void*)g,
                                   (__attribute__((address_space(3))) void*)l, 16, 0, 0);
}

// DPP 16-lane reductions — pure VALU
template<int C> __device__ __forceinline__ float dpp_mov_f(float x){
  union{float f;int i;} u; u.f=x;
  u.i = __builtin_amdgcn_mov_dpp(u.i, C, 0xf, 0xf, true);
  return u.f;
}
__device__ __forceinline__ float red16_add(float x){
  x = x + dpp_mov_f<0xB1>(x);
  x = x + dpp_mov_f<0x4E>(x);
  x = x + dpp_mov_f<0x141>(x);
  x = x + dpp_mov_f<0x140>(x);
  return x;
}

// ------------- merged prep: weight transpose+cvt(+q-scale), enc cvt, ln1,
//               scaled-bias copies --------------------------------------
__global__ void prep_all(const float* __restrict__ s0,const float* __restrict__ s1,
                         const float* __restrict__ s2,const float* __restrict__ s3,
                         const float* __restrict__ s4,const float* __restrict__ s5,
                         u16* __restrict__ d0,u16* __restrict__ d1,
                         u16* __restrict__ d2,u16* __restrict__ d3,
                         u16* __restrict__ d4,u16* __restrict__ d5,
                         const float* __restrict__ enc, u16* __restrict__ enc_bf,
                         const float* __restrict__ xin, const float* __restrict__ g1,
                         const float* __restrict__ b1, u16* __restrict__ hbuf,
                         const float* __restrict__ attn_b, const float* __restrict__ cross_b,
                         float* __restrict__ sb_attn, float* __restrict__ sb_cross){
  __shared__ u16 tile[64][68];
  int id=blockIdx.x;
  if(id>=5894){
    int i=(id-5894)*256+threadIdx.x;
    if(i<2304)      sb_attn[i]       = attn_b[i]       *((i     <768)?0.125f:1.f);
    else if(i<4608) sb_cross[i-2304] = cross_b[i-2304] *((i-2304<768)?0.125f:1.f);
    return;
  }
  if(id>=3846){
    // ---- ln1 ----
    int row  = (id-3846)*4 + (threadIdx.x>>6);
    int lane = threadIdx.x&63;
    size_t base = (size_t)row*N_EMBD;
    float v[12];
#pragma unroll
    for(int p=0;p<3;p++){
      int col = p*256 + lane*4;
      float4 f = *(const float4*)&xin[base+col];
      v[p*4]=f.x; v[p*4+1]=f.y; v[p*4+2]=f.z; v[p*4+3]=f.w;
    }
    float s=0.f, s2=0.f;
#pragma unroll
    for(int i=0;i<12;i++){ s+=v[i]; s2+=v[i]*v[i]; }
#pragma unroll
    for(int off=1; off<64; off<<=1){ s += __shfl_xor(s,off); s2 += __shfl_xor(s2,off); }
    float mean = s*(1.f/N_EMBD);
    float var  = s2*(1.f/N_EMBD) - mean*mean;
    float rstd = rsqrtf(var + 1e-5f);
#pragma unroll
    for(int p=0;p<3;p++){
      int col = p*256 + lane*4;
#pragma unroll
      for(int j=0;j<4;j++){
        hbuf[base+col+j] = f2b((v[p*4+j]-mean)*rstd*g1[col+j] + b1[col+j]);
      }
    }
    return;
  }
  if(id>=2304){
    // ---- enc convert ----
    int i = (id-2304)*256 + threadIdx.x;
    float4 f = *(const float4*)&enc[i*4];
    ushort4 u; u.x=f2b(f.x); u.y=f2b(f.y); u.z=f2b(f.z); u.w=f2b(f.w);
    *(ushort4*)&enc_bf[i*4] = u;
    return;
  }
  // ---- weight transpose (+ 0.125 fold on q-columns of attn_w/cross_w) ----
  const float* in; u16* out; int K,N,t;
  if(id<432)      {in=s0;out=d0;K=768;N=2304;t=id;}
  else if(id<864) {in=s1;out=d1;K=768;N=2304;t=id-432;}
  else if(id<1008){in=s2;out=d2;K=768;N=768;t=id-864;}
  else if(id<1152){in=s3;out=d3;K=768;N=768;t=id-1008;}
  else if(id<1728){in=s4;out=d4;K=768;N=3072;t=id-1152;}
  else            {in=s5;out=d5;K=3072;N=768;t=id-1728;}
  int tiles_n=N>>6;
  int k0=(t/tiles_n)<<6, n0=(t%tiles_n)<<6;
  float qs = (id<864 && n0<768) ? 0.125f : 1.f;   // whole 64-tile inside q-part
  int tr = threadIdx.x>>4;
  int tc = (threadIdx.x&15)*4;
#pragma unroll
  for(int i=0;i<4;i++){
    float4 f = *(const float4*)&in[(size_t)(k0+tr+i*16)*N + n0 + tc];
    tile[tr+i*16][tc+0]=f2b(f.x*qs); tile[tr+i*16][tc+1]=f2b(f.y*qs);
    tile[tr+i*16][tc+2]=f2b(f.z*qs); tile[tr+i*16][tc+3]=f2b(f.w*qs);
  }
  __syncthreads();
#pragma unroll
  for(int i=0;i<4;i++){
    int n = n0+tr+i*16;
    ushort4 u;
    u.x=tile[tc+0][tr+i*16]; u.y=tile[tc+1][tr+i*16];
    u.z=tile[tc+2][tr+i*16]; u.w=tile[tc+3][tr+i*16];
    *(ushort4*)&out[(size_t)n*K + k0 + tc] = u;
  }
}

// ------------- layernorm: one wave per row of 768, f32 in -> bf16 out -----
__global__ void ln_kernel(const float* __restrict__ x, const float* __restrict__ g,
                          const float* __restrict__ bta, u16* __restrict__ out){
  int row  = blockIdx.x*4 + (threadIdx.x>>6);
  int lane = threadIdx.x&63;
  size_t base = (size_t)row*N_EMBD;
  float v[12];
#pragma unroll
  for(int p=0;p<3;p++){
    int col = p*256 + lane*4;
    float4 f = *(const float4*)&x[base+col];
    v[p*4]=f.x; v[p*4+1]=f.y; v[p*4+2]=f.z; v[p*4+3]=f.w;
  }
  float s=0.f, s2=0.f;
#pragma unroll
  for(int i=0;i<12;i++){ s+=v[i]; s2+=v[i]*v[i]; }
#pragma unroll
  for(int off=1; off<64; off<<=1){ s += __shfl_xor(s,off); s2 += __shfl_xor(s2,off); }
  float mean = s*(1.f/N_EMBD);
  float var  = s2*(1.f/N_EMBD) - mean*mean;
  float rstd = rsqrtf(var + 1e-5f);
#pragma unroll
  for(int p=0;p<3;p++){
    int col = p*256 + lane*4;
#pragma unroll
    for(int j=0;j<4;j++){
      out[base+col+j] = f2b((v[p*4+j]-mean)*rstd*g[col+j] + bta[col+j]);
    }
  }
}

// ---------------- GEMM: C = A(M,K) @ Wt(N,K)^T + bias, fused epilogues ----
// BM=128, BK=64, BN in {64,128}. XOR-swizzled LDS. Round-4 proven operating
// point (measured best; dbuf r2, split-K r6, BK=128 r7 all regressed).
enum { M_QKV_SELF=0, M_Q_CROSS=1, M_KV_CROSS=2, M_RESID_F32=3,
       M_RESID_INPLACE=4, M_GELU=5, M_RESID_OUT=6 };

template<int MODE, int BN>
__device__ __forceinline__ void gemm_body(u16* __restrict__ As, u16* __restrict__ Bs,
                        const u16* __restrict__ A, const u16* __restrict__ Wt,
                        const float* __restrict__ bias,
                        void* out0, void* out1, void* out2, const void* resid,
                        int M, int K, int Ntiles, int Mtl, int bid){
  constexpr int MI = (BN==128)?4:2;
  int tid=threadIdx.x, wave=tid>>6, lane=tid&63;

  int mt, nt;
  if((Mtl&7)==0){
    int xcd=bid&7, j=bid>>3, bpx=Mtl>>3;
    int band=j/Ntiles; nt=j-band*Ntiles; mt=xcd*bpx+band;
  } else { mt=bid/Ntiles; nt=bid-mt*Ntiles; }
  int m0=mt*128, n0=nt*BN;

  int wm = (BN==128)? (wave>>1)*64 : wave*32;
  int wn = (BN==128)? (wave&1)*64  : 0;
  int lrow=lane&15, quad=lane>>4;
  f32x4 acc[MI][4];
  f32x4 z = {0.f,0.f,0.f,0.f};
#pragma unroll
  for(int i=0;i<MI;i++)
#pragma unroll
    for(int j=0;j<4;j++) acc[i][j]=z;

  int srow  = wave*8 + (lane>>3);
  int c_src = (lane&7) ^ ((lane>>3)&7);
  int pa = quad ^ (lrow&7);

  // hoisted K-invariant stage base pointers (clamp + row*K done once)
  const u16* ap[4];
#pragma unroll
  for(int i=0;i<4;i++){
    int ga = min(m0 + i*32 + srow, M-1);
    ap[i] = A + (size_t)ga*K + c_src*8;
  }
  const u16* bp[BN/32];
#pragma unroll
  for(int i=0;i<BN/32;i++)
    bp[i] = Wt + (size_t)(n0 + i*32 + srow)*K + c_src*8;

  for(int k0=0;k0<K;k0+=64){
#pragma unroll
    for(int i=0;i<4;i++)
      gl_lds16(ap[i] + k0, &As[(i*32+wave*8)*64]);
#pragma unroll
    for(int i=0;i<BN/32;i++)
      gl_lds16(bp[i] + k0, &Bs[(i*32+wave*8)*64]);
    __syncthreads();
    bf16x8 af[MI][2], bfr[4][2];
#pragma unroll
    for(int i=0;i<MI;i++){
      const u16* ab=&As[(wm+i*16+lrow)*64];
      af[i][0]=*(const bf16x8*)(ab+pa*8);
      af[i][1]=*(const bf16x8*)(ab+(pa^4)*8);
    }
#pragma unroll
    for(int i=0;i<4;i++){
      const u16* bb=&Bs[(wn+i*16+lrow)*64];
      bfr[i][0]=*(const bf16x8*)(bb+pa*8);
      bfr[i][1]=*(const bf16x8*)(bb+(pa^4)*8);
    }
#pragma unroll
    for(int h=0;h<2;h++)
#pragma unroll
      for(int mi=0;mi<MI;mi++)
#pragma unroll
        for(int ni=0;ni<4;ni++)
          acc[mi][ni] = __builtin_amdgcn_mfma_f32_16x16x32_bf16(af[mi][h], bfr[ni][h], acc[mi][ni], 0,0,0);
    __syncthreads();
  }

#pragma unroll
  for(int ni=0;ni<4;ni++){
    int n = n0 + wn + ni*16 + lrow;
    float bv = bias[n];
#pragma unroll
    for(int mi=0;mi<MI;mi++){
      int mbase = m0 + wm + mi*16 + quad*4;
      float cr[4];
#pragma unroll
      for(int r=0;r<4;r++) cr[r]=acc[mi][ni][r]+bv;

      if constexpr (MODE==M_QKV_SELF){
        int part=n/768, nn=n-part*768;
        int hh=nn>>6, dd=nn&63;
        int b=mbase>>10, t0=mbase&1023;
        size_t bh=(size_t)(b*NH+hh);
        if(part==0){   // q pre-scaled by 0.125 via weight/bias fold
#pragma unroll
          for(int r=0;r<4;r++) ((u16*)out0)[(bh*T_LEN+t0+r)*HD+dd]=f2b(cr[r]);
        } else if(part==1){
#pragma unroll
          for(int r=0;r<4;r++) ((u16*)out1)[(bh*T_LEN+t0+r)*HD+dd]=f2b(cr[r]);
        } else {
          ushort4 pk; pk.x=f2b(cr[0]); pk.y=f2b(cr[1]); pk.z=f2b(cr[2]); pk.w=f2b(cr[3]);
          *(ushort4*)&((u16*)out2)[(bh*HD+dd)*T_LEN+t0]=pk;
        }
      } else if constexpr (MODE==M_Q_CROSS){
        int b=mbase>>10, t0=mbase&1023;
        int hh=n>>6, dd=n&63;
        size_t bh=(size_t)(b*NH+hh);
#pragma unroll
        for(int r=0;r<4;r++) ((u16*)out0)[(bh*T_LEN+t0+r)*HD+dd]=f2b(cr[r]);
      } else if constexpr (MODE==M_KV_CROSS){
        int part=n/768, nn=n-part*768;
        int hh=nn>>6, dd=nn&63;
#pragma unroll
        for(int r=0;r<4;r++){
          int m=mbase+r;
          if(m<M){
            int b=m/S_LEN, s=m-b*S_LEN;
            size_t bh=(size_t)(b*NH+hh);
            if(part==0) ((u16*)out0)[(bh*S_PAD+s)*HD+dd]=f2b(cr[r]);
            else        ((u16*)out1)[(bh*HD+dd)*S_PAD+s]=f2b(cr[r]);
          }
        }
      } else if constexpr (MODE==M_RESID_F32){
        const float* x=(const float*)resid;
#pragma unroll
        for(int r=0;r<4;r++){ int m=mbase+r;
          ((float*)out0)[(size_t)m*768+n]=x[(size_t)m*768+n]+cr[r]; }
      } else if constexpr (MODE==M_RESID_INPLACE){
#pragma unroll
        for(int r=0;r<4;r++){ int m=mbase+r;
          ((float*)out0)[(size_t)m*768+n]+=cr[r]; }
      } else if constexpr (MODE==M_GELU){
#pragma unroll
        for(int r=0;r<4;r++){
          int m=mbase+r;
          float uu=cr[r];
          float zz=0.7978845608028654f*(uu+0.044715f*uu*uu*uu);
          float e=__expf(fminf(2.f*zz, 80.f));
          ((u16*)out0)[(size_t)m*3072+n]=f2b(uu*e*__builtin_amdgcn_rcpf(e+1.f));
        }
      } else { // M_RESID_OUT -> float32 output
        const float* x=(const float*)resid;
#pragma unroll
        for(int r=0;r<4;r++){ int m=mbase+r;
          ((float*)out0)[(size_t)m*768+n]=x[(size_t)m*768+n]+cr[r]; }
      }
    }
  }
}

template<int MODE, int BN>
__global__ __launch_bounds__(256,3)
void gemm_bt(const u16* __restrict__ A, const u16* __restrict__ Wt,
             const float* __restrict__ bias,
             void* out0, void* out1, void* out2, const void* resid,
             int M, int K, int Ntiles){
  __shared__ u16 As[128*64];
  __shared__ u16 Bs[BN*64];
  gemm_body<MODE,BN>(As,Bs,A,Wt,bias,out0,out1,out2,resid,M,K,Ntiles,
                     gridDim.x/Ntiles, blockIdx.x);
}

// Q_cross (768 blocks) + KV_cross (408 blocks) fused into one launch.
__global__ __launch_bounds__(256,3)
void gemm_cross(const u16* __restrict__ hbuf, const u16* __restrict__ cwT,
                const float* __restrict__ sbc, const u16* __restrict__ encbf,
                void* Qc, void* Kc, void* Vct){
  __shared__ u16 As[128*64];
  __shared__ u16 Bs[64*64];
  if(blockIdx.x<768)
    gemm_body<M_Q_CROSS,64>(As,Bs,hbuf,cwT,sbc,Qc,nullptr,nullptr,nullptr,
                            8192,768,12, 64, blockIdx.x);
  else
    gemm_body<M_KV_CROSS,64>(As,Bs,encbf,cwT+768*768,sbc+768,Kc,Vct,nullptr,nullptr,
                             2056,768,24, 17, blockIdx.x-768);
}

// ---------------- flash attention v6: QBLK=128 (32 q-rows/wave) ------------
// Same proven sync structure as v4 (LDS-staged K/V, double-buffered, 2
// barriers/tile, fixed-max softmax). Each wave now owns TWO 16-row fragment
// groups: staging (4 gl_lds16/wave/tile) and K/V fragment reads (16
// ds_read_b128) amortize over 2x the MFMA (32 vs 16), barriers per unit work
// halve, and the causal grid drops 1536->768 = exactly 3 blocks/CU (LDS
// 50.4KB) -> one dispatch round. Extra fully-masked tiles on low waves
// contribute exact zeros (P=exp(-3e38)=0; causal V fully initialized).
template<bool CAUSAL>
__global__ __launch_bounds__(256,3)
void flash_attn(const u16* __restrict__ Q, const u16* __restrict__ Kk,
                const u16* __restrict__ V, u16* __restrict__ O,
                int Skey, int Spad){
  __shared__ u16 KT[2][64*64];
  __shared__ u16 VT[2][64*64];
  __shared__ u16 Plds[4][32][72];
  int bh = blockIdx.x % BH;
  int qbi= blockIdx.x / BH;                  // 0..7
  int qb = CAUSAL ? (7-qbi) : qbi;           // heavy blocks dispatched first
  int b=bh/NH, hh=bh-b*NH;
  int wave=threadIdx.x>>6, lane=threadIdx.x&63;
  int lrow=lane&15, quad=lane>>4;
  const u16* Qp=Q+(size_t)bh*T_LEN*HD;
  const u16* Kp=Kk+(size_t)bh*Spad*HD;
  const u16* Vp=V+(size_t)bh*HD*Spad;
  u16* Op=O+(size_t)b*T_LEN*N_EMBD+hh*HD;
  int q0 = qb*128 + wave*32;                 // 32 rows per wave

  int r0    = wave*8 + (lane>>3);
  int c_src = (lane&7) ^ ((lane>>3)&7);

  bf16x8 aq[2][2];
#pragma unroll
  for(int sg=0;sg<2;sg++){
    aq[sg][0]=*(const bf16x8*)&Qp[(size_t)(q0+sg*16+lrow)*HD + quad*8];
    aq[sg][1]=*(const bf16x8*)&Qp[(size_t)(q0+sg*16+lrow)*HD + 32 + quad*8];
  }

  f32x4 oacc[2][4];
  f32x4 z={0.f,0.f,0.f,0.f};
#pragma unroll
  for(int sg=0;sg<2;sg++)
#pragma unroll
    for(int i=0;i<4;i++) oacc[sg][i]=z;
  float lsum[2][4]={{0.f,0.f,0.f,0.f},{0.f,0.f,0.f,0.f}};

  int nt = CAUSAL ? (2*qb+2) : ((Skey+63)>>6);

  {
    gl_lds16(Kp + (size_t)r0*HD        + c_src*8, &KT[0][(wave*8)*64]);
    gl_lds16(Kp + (size_t)(r0+32)*HD   + c_src*8, &KT[0][(32+wave*8)*64]);
    gl_lds16(Vp + (size_t)r0*Spad      + c_src*8, &VT[0][(wave*8)*64]);
    gl_lds16(Vp + (size_t)(r0+32)*Spad + c_src*8, &VT[0][(32+wave*8)*64]);
  }
  __syncthreads();

  int p0 = quad ^ (lrow&7);

  for(int it=0; it<nt; it++){
    int bb = it&1;
    int kt = it*64;
    if(it+1<nt){
      int ktn=(it+1)*64;
      gl_lds16(Kp + (size_t)(ktn+r0)*HD      + c_src*8, &KT[bb^1][(wave*8)*64]);
      gl_lds16(Kp + (size_t)(ktn+r0+32)*HD   + c_src*8, &KT[bb^1][(32+wave*8)*64]);
      gl_lds16(Vp + (size_t)r0*Spad      + ktn + c_src*8, &VT[bb^1][(wave*8)*64]);
      gl_lds16(Vp + (size_t)(r0+32)*Spad + ktn + c_src*8, &VT[bb^1][(32+wave*8)*64]);
    }
    // K fragments read once, used by both row groups
    bf16x8 bk[4][2];
#pragma unroll
    for(int g=0;g<4;g++){
      const u16* kb=&KT[bb][(g*16+lrow)*64];
      bk[g][0]=*(const bf16x8*)(kb+p0*8);
      bk[g][1]=*(const bf16x8*)(kb+(p0^4)*8);
    }
    f32x4 sc[2][4];
#pragma unroll
    for(int sg=0;sg<2;sg++)
#pragma unroll
      for(int g=0;g<4;g++){
        sc[sg][g]=z;
        sc[sg][g]=__builtin_amdgcn_mfma_f32_16x16x32_bf16(aq[sg][0],bk[g][0],sc[sg][g],0,0,0);
        sc[sg][g]=__builtin_amdgcn_mfma_f32_16x16x32_bf16(aq[sg][1],bk[g][1],sc[sg][g],0,0,0);
      }
#pragma unroll
    for(int sg=0;sg<2;sg++){
      // skip masking only when every k in the tile <= every row of this group
      bool dm = CAUSAL ? (kt+63 > q0+sg*16) : (kt+63 >= Skey);
#pragma unroll
      for(int r=0;r<4;r++){
        float sv0=sc[sg][0][r], sv1=sc[sg][1][r], sv2=sc[sg][2][r], sv3=sc[sg][3][r];
        if(dm){
          if(CAUSAL){
            int q=q0+sg*16+quad*4+r;
            if(kt+lrow    >q) sv0=-3.0e38f;
            if(kt+16+lrow >q) sv1=-3.0e38f;
            if(kt+32+lrow >q) sv2=-3.0e38f;
            if(kt+48+lrow >q) sv3=-3.0e38f;
          } else {
            if(kt+lrow    >=Skey) sv0=-3.0e38f;
            if(kt+16+lrow >=Skey) sv1=-3.0e38f;
            if(kt+32+lrow >=Skey) sv2=-3.0e38f;
            if(kt+48+lrow >=Skey) sv3=-3.0e38f;
          }
        }
        float p0e=__expf(sv0), p1e=__expf(sv1);
        float p2e=__expf(sv2), p3e=__expf(sv3);
        lsum[sg][r] += (p0e+p1e)+(p2e+p3e);
        Plds[wave][sg*16+quad*4+r][lrow]    = f2b(p0e);
        Plds[wave][sg*16+quad*4+r][16+lrow] = f2b(p1e);
        Plds[wave][sg*16+quad*4+r][32+lrow] = f2b(p2e);
        Plds[wave][sg*16+quad*4+r][48+lrow] = f2b(p3e);
      }
    }
    bf16x8 ap[2][2];
#pragma unroll
    for(int sg=0;sg<2;sg++){
      ap[sg][0]=*(const bf16x8*)&Plds[wave][sg*16+lrow][quad*8];
      ap[sg][1]=*(const bf16x8*)&Plds[wave][sg*16+lrow][32+quad*8];
    }
#pragma unroll
    for(int dt=0;dt<4;dt++){
      const u16* vb=&VT[bb][(dt*16+lrow)*64];
      bf16x8 bv0=*(const bf16x8*)(vb+p0*8);
      bf16x8 bv1=*(const bf16x8*)(vb+(p0^4)*8);
#pragma unroll
      for(int sg=0;sg<2;sg++){
        oacc[sg][dt]=__builtin_amdgcn_mfma_f32_16x16x32_bf16(ap[sg][0],bv0,oacc[sg][dt],0,0,0);
        oacc[sg][dt]=__builtin_amdgcn_mfma_f32_16x16x32_bf16(ap[sg][1],bv1,oacc[sg][dt],0,0,0);
      }
    }
    __syncthreads();
  }
#pragma unroll
  for(int sg=0;sg<2;sg++){
    float linv[4];
#pragma unroll
    for(int r=0;r<4;r++) linv[r]=1.f/red16_add(lsum[sg][r]);
#pragma unroll
    for(int dt=0;dt<4;dt++){
#pragma unroll
      for(int r=0;r<4;r++){
        int q=q0+sg*16+quad*4+r;
        Op[(size_t)q*N_EMBD + dt*16 + lrow]=f2b(oacc[sg][dt][r]*linv[r]);
      }
    }
  }
}

// ---------------------------------------------------------------------------
extern "C" void kernel_launch(void* const* d_in, const int* in_sizes, int n_in,
                              void* d_out, int out_size, void* d_ws, size_t ws_size,
                              hipStream_t stream){
  const float* x_in   =(const float*)d_in[0];
  const float* enc    =(const float*)d_in[1];
  const float* ln1_g  =(const float*)d_in[2];
  const float* ln1_b  =(const float*)d_in[3];
  const float* ln2_g  =(const float*)d_in[4];
  const float* ln2_b  =(const float*)d_in[5];
  const float* ln3_g  =(const float*)d_in[6];
  const float* ln3_b  =(const float*)d_in[7];
  const float* attn_w =(const float*)d_in[8];
  const float* attn_b =(const float*)d_in[9];
  const float* attn_pw=(const float*)d_in[10];
  const float* attn_pb=(const float*)d_in[11];
  const float* cross_w=(const float*)d_in[12];
  const float* cross_b=(const float*)d_in[13];
  const float* cross_pw=(const float*)d_in[14];
  const float* cross_pb=(const float*)d_in[15];
  const float* fc_w   =(const float*)d_in[16];
  const float* fc_b   =(const float*)d_in[17];
  const float* proj_w =(const float*)d_in[18];
  const float* proj_b =(const float*)d_in[19];

  char* ws=(char*)d_ws;
  u16*  attn_wT  =(u16*)(ws + 0);           // 2304x768 bf16 (q-part pre-scaled)
  u16*  cross_wT =(u16*)(ws + 3538944);     // 2304x768    (q-part pre-scaled)
  u16*  attn_pwT =(u16*)(ws + 7077888);     // 768x768
  u16*  cross_pwT=(u16*)(ws + 8257536);     // 768x768
  u16*  fc_wT    =(u16*)(ws + 9437184);     // 3072x768
  u16*  proj_wT  =(u16*)(ws + 14155776);    // 768x3072
  float* xcur    =(float*)(ws + 18874368);  // 8192x768 f32
  u16*  hbuf     =(u16*)(ws + 44040192);    // 8192x768 bf16 (LN out / attn out)
  u16*  Qs       =(u16*)(ws + 56623104);    // 96x1024x64
  u16*  Ks       =(u16*)(ws + 69206016);
  u16*  Vst      =(u16*)(ws + 81788928);
  u16*  Qc       =(u16*)(ws + 94371840);
  u16*  hf       =(u16*)(ws + 56623104);    // 8192x3072, reuses Qs..Qc (MLP phase)
  u16*  Kc       =(u16*)(ws + 106954752);   // 96x320x64
  u16*  Vct      =(u16*)(ws + 110886912);   // 96x64x320
  u16*  enc_bf   =(u16*)(ws + 114819072);   // 2056x768 bf16
  float* sb_attn =(float*)(ws + 117977088); // 2304 f32 (q-part x0.125)
  float* sb_cross=(float*)(ws + 117986304); // 2304 f32 (q-part x0.125)

  dim3 blk(256);
  // merged: weight transpose (2304) + enc cvt (1542) + ln1 (2048) + bias (18)
  prep_all<<<5912,blk,0,stream>>>(attn_w, cross_w, attn_pw, cross_pw, fc_w, proj_w,
                                  attn_wT, cross_wT, attn_pwT, cross_pwT, fc_wT, proj_wT,
                                  enc, enc_bf, x_in, ln1_g, ln1_b, hbuf,
                                  attn_b, cross_b, sb_attn, sb_cross);

  // self-attention
  gemm_bt<M_QKV_SELF,128><<<1152,blk,0,stream>>>(hbuf, attn_wT, sb_attn,
      Qs, Ks, Vst, nullptr, 8192, 768, 18);
  flash_attn<true><<<768,blk,0,stream>>>(Qs, Ks, Vst, hbuf, 1024, 1024);
  gemm_bt<M_RESID_F32,64><<<768,blk,0,stream>>>(hbuf, attn_pwT, attn_pb,
      xcur, nullptr, nullptr, x_in, 8192, 768, 12);

  // cross-attention
  ln_kernel<<<2048,blk,0,stream>>>(xcur, ln2_g, ln2_b, hbuf);
  gemm_cross<<<1176,blk,0,stream>>>(hbuf, cross_wT, sb_cross, enc_bf, Qc, Kc, Vct);
  flash_attn<false><<<768,blk,0,stream>>>(Qc, Kc, Vct, hbuf, S_LEN, S_PAD);
  gemm_bt<M_RESID_INPLACE,64><<<768,blk,0,stream>>>(hbuf, cross_pwT, cross_pb,
      xcur, nullptr, nullptr, nullptr, 8192, 768, 12);

  // MLP
  ln_kernel<<<2048,blk,0,stream>>>(xcur, ln3_g, ln3_b, hbuf);
  gemm_bt<M_GELU,128><<<1536,blk,0,stream>>>(hbuf, fc_wT, fc_b,
      hf, nullptr, nullptr, nullptr, 8192, 768, 24);
  gemm_bt<M_RESID_OUT,64><<<768,blk,0,stream>>>(hf, proj_wT, proj_b,
      d_out, nullptr, nullptr, xcur, 8192, 3072, 12);
}